// Round 10
// baseline (2701.057 us; speedup 1.0000x reference)
//
#include <hip/hip_runtime.h>

#define Bsz 128
#define Lseq 512
#define Hdim 256
#define Tn 16
#define START_TAG 14
#define END_TAG 15

typedef float f32x4 __attribute__((ext_vector_type(4)));
typedef short s16x8 __attribute__((ext_vector_type(8)));

__device__ __forceinline__ unsigned short f2bf(float f) {
    unsigned int u = __builtin_bit_cast(unsigned int, f);
    u += 0x7fffu + ((u >> 16) & 1u);          // RNE
    return (unsigned short)(u >> 16);
}
__device__ __forceinline__ float bf2f(unsigned int bits16) {
    return __builtin_bit_cast(float, bits16 << 16);
}
__device__ __forceinline__ float sigmoidf_(float x) {
    return 1.0f / (1.0f + __expf(-x));
}

// Raw workgroup barrier WITHOUT the vmcnt(0) drain __syncthreads forces:
// orders LDS (lgkmcnt) only, leaves global loads in flight across the barrier.
// sched_barrier(0) fences prevent hipcc hoisting/sinking around the asm (rule #18).
__device__ __forceinline__ void wg_barrier_lds() {
    __builtin_amdgcn_sched_barrier(0);
    asm volatile("s_waitcnt lgkmcnt(0)" ::: "memory");
    __builtin_amdgcn_sched_barrier(0);
    __builtin_amdgcn_s_barrier();
    __builtin_amdgcn_sched_barrier(0);
}

// emb fp32 [V*256] -> packed bf16 pairs [V*128]
__global__ void embprep_kernel(const float* __restrict__ emb,
                               unsigned int* __restrict__ embb, int n2) {
    int i = blockIdx.x * blockDim.x + threadIdx.x;
    int stride = gridDim.x * blockDim.x;
    for (; i < n2; i += stride)
        embb[i] = (unsigned int)f2bf(emb[2 * i]) | ((unsigned int)f2bf(emb[2 * i + 1]) << 16);
}

// wtile[dir][ug(16)][tl=gate(4)][ki(16)][lane(64)][4 uints] : MFMA B-frag order.
__global__ void wprep_kernel(const float* __restrict__ wih_f, const float* __restrict__ whh_f,
                             const float* __restrict__ wih_b, const float* __restrict__ whh_b,
                             unsigned int* __restrict__ wtile) {
    int bid = blockIdx.x;                 // ((dir*16+ug)*4+tl)*16+ki
    int ki  = bid & 15;
    int tl  = (bid >> 4) & 3;
    int ug  = (bid >> 6) & 15;
    int dir = bid >> 10;
    int t = threadIdx.x;                  // 256 = lane(64) x j(4)
    int lane = t >> 2, j = t & 3;
    int n = lane & 15, kq = lane >> 4;
    int k0 = ki * 32 + kq * 8 + 2 * j;
    int col = tl * 256 + ug * 16 + n;
    const float* wih = dir ? wih_b : wih_f;
    const float* whh = dir ? whh_b : whh_f;
    float f0, f1;
    if (k0 < 256) { f0 = wih[col * 256 + k0];       f1 = wih[col * 256 + k0 + 1]; }
    else          { f0 = whh[col * 256 + k0 - 256]; f1 = whh[col * 256 + k0 - 255]; }
    wtile[(size_t)bid * 256 + t] = (unsigned int)f2bf(f0) | ((unsigned int)f2bf(f1) << 16);
}

__global__ void lengths_kernel(const int* __restrict__ tag, int* __restrict__ lengths) {
    int b = blockIdx.x;
    int tid = threadIdx.x;
    int cnt = 0;
    for (int l = tid; l < Lseq; l += blockDim.x)
        cnt += (tag[b * Lseq + l] != 0) ? 1 : 0;
    for (int off = 32; off > 0; off >>= 1) cnt += __shfl_down(cnt, off);
    __shared__ int red[4];
    if ((tid & 63) == 0) red[tid >> 6] = cnt;
    __syncthreads();
    if (tid == 0) lengths[b] = red[0] + red[1] + red[2] + red[3];
}

// Persistent BiLSTM, 256 WGs (1/CU). WG = dir(2) x bg(8: 16 batches) x ug(16: 16 units).
// TWO-STREAM half-step pipeline: batches split into stream A (rows 0-7) and
// stream B (rows 8-15); recurrence is batch-independent. Half i runs stream
// sg=i&1 at step s=i>>1. MFMA tiles stay 16x16 (inactive rows = garbage,
// never consumed). While sg computes, the OTHER stream's tagged ring data
// (stored one half earlier) plus sg's embb gather fly across drain-free raw
// barriers (lgkmcnt-only), so both RTTs are covered by compute. Tag-in-data
// protocol identical to r9: word = (bf16 pair | (s+1)<<32), relaxed agent
// atomics, quick first retry then s_sleep(2) backoff. Safety: peer stored
// s+1 => peer already consumed s => overwriting parity slot (s+2)&1 is safe.
__global__ __launch_bounds__(256, 1) void bilstm_persist(
    const int* __restrict__ bd,
    const unsigned int* __restrict__ embb,         // [V][128]
    const unsigned int* __restrict__ wtile,        // frag-ordered weights
    const float* __restrict__ b_f, const float* __restrict__ b_b,
    const float* __restrict__ w_cls,
    float* __restrict__ em_f, float* __restrict__ em_b,
    unsigned long long* __restrict__ ring)         // [2 dir][2 par][128 b][128 words]
{
    const int wg  = blockIdx.x;
    const int dir = wg >> 7;
    const int bg  = (wg >> 4) & 7;
    const int ug  = wg & 15;
    const int tid = threadIdx.x;
    const int gb0 = bg * 16;

    __shared__ unsigned int w_lds[16384];      // [4 tl][16 ki][64 lane][4]
    __shared__ unsigned int h_lds[16 * 132];   // [16 m][128 uints + 4 pad]
    __shared__ float g_lds[4][16][17];
    __shared__ float part_lds[16][17];
    __shared__ float bias_lds[64];
    __shared__ float wcls_lds[256];

    // ---- one-time staging ----
    {
        const unsigned int* wsrc = wtile + ((size_t)(dir * 16 + ug) << 14);
        for (int i = 0; i < 16; ++i) {
            int idx = tid + 256 * i;
            uint4 v4 = *(const uint4*)(wsrc + (size_t)idx * 4);
            *(uint4*)&w_lds[idx * 4] = v4;
        }
        if (tid < 64) {
            const float* bias = dir ? b_b : b_f;
            bias_lds[tid] = bias[(tid >> 4) * 256 + ug * 16 + (tid & 15)];
        }
        wcls_lds[tid] = w_cls[(size_t)ug * (2 * Hdim) + dir * Hdim + tid];
        for (int i = tid; i < 16 * 132; i += 256) h_lds[i] = 0;   // h_{-1}=0 both streams
    }

    // identities
    const int wv = tid >> 6;        // wave = gate
    const int l  = tid & 63;
    const int n  = l & 15;          // MFMA row (batch) / col (unit)
    const int kq = l >> 4;
    const int cb = tid >> 4, cu = tid & 15;      // cell: (batch abs, unit)
    const int rrow = tid >> 5;                   // ring slice: local row 0..7
    const int rw0  = (tid & 31) * 4;             //            word offset
    float c_reg = 0.f;                           // c for batch cb (one stream)
    float* emout = dir ? em_b : em_f;

    unsigned long long* rbase = ring + (size_t)dir * 2 * 16384;

    __syncthreads();   // staging ready (one-time full drain is fine)

    // ---- prologue: acc_x for both streams at step 0; tokens for step 1 ----
    f32x4 acc_xA = {0.f, 0.f, 0.f, 0.f};
    f32x4 acc_xB = {0.f, 0.f, 0.f, 0.f};
    {
        const int t0 = dir ? (Lseq - 1) : 0;
        int tokA = bd[(size_t)(gb0 + (n & 7)) * Lseq + t0];
        int tokB = bd[(size_t)(gb0 + 8 + (n & 7)) * Lseq + t0];
        const unsigned int* xa = embb + (size_t)tokA * 128 + kq * 4;
        const unsigned int* xb = embb + (size_t)tokB * 128 + kq * 4;
        #pragma unroll
        for (int ki = 0; ki < 8; ++ki) {
            s16x8 b = *(const s16x8*)&w_lds[((wv * 16 + ki) * 64 + l) * 4];
            s16x8 aA = __builtin_bit_cast(s16x8, *(const uint4*)(xa + ki * 16));
            acc_xA = __builtin_amdgcn_mfma_f32_16x16x32_bf16(aA, b, acc_xA, 0, 0, 0);
            s16x8 aB = __builtin_bit_cast(s16x8, *(const uint4*)(xb + ki * 16));
            acc_xB = __builtin_amdgcn_mfma_f32_16x16x32_bf16(aB, b, acc_xB, 0, 0, 0);
        }
    }
    const int t1 = dir ? (Lseq - 2) : 1;
    int tokA_next = (Lseq > 1) ? bd[(size_t)(gb0 + (n & 7)) * Lseq + t1] : 0;
    int tokB_next = (Lseq > 1) ? bd[(size_t)(gb0 + 8 + (n & 7)) * Lseq + t1] : 0;

    unsigned long long v[4];    // validated ring words (4/thread, 8-row slice)

    for (int i = 0; i < 2 * Lseq; ++i) {
        const int sg = i & 1;           // stream of this half
        const int s  = i >> 1;          // stream-step

        // ---- A: commit sg's validated h_{s-1} -> its 8 LDS rows ----
        if (s > 0) {
            int row = sg * 8 + rrow;
            #pragma unroll
            for (int j = 0; j < 4; ++j)
                h_lds[row * 132 + rw0 + j] = (unsigned int)v[j];
        }

        // ---- P: early probe of the OTHER stream's step (stored last half) ----
        const unsigned long long* psrc = nullptr;
        if (i >= 1) {
            const int ps = (i - 1) >> 1;
            psrc = rbase + (size_t)(ps & 1) * 16384
                 + (size_t)(gb0 + (sg ^ 1) * 8 + rrow) * 128 + rw0;
            #pragma unroll
            for (int j = 0; j < 4; ++j)
                v[j] = __hip_atomic_load(psrc + j, __ATOMIC_RELAXED, __HIP_MEMORY_SCOPE_AGENT);
        }

        // ---- X: issue sg's x-gather for step s+1 (flies across barriers) ----
        uint4 xg[8];
        const bool do_x = (s + 1 < Lseq);
        if (do_x) {
            int tok = sg ? tokB_next : tokA_next;
            const unsigned int* xsrc = embb + (size_t)tok * 128 + kq * 4;
            #pragma unroll
            for (int ki = 0; ki < 8; ++ki)
                xg[ki] = *(const uint4*)(xsrc + ki * 16);
        }

        wg_barrier_lds();   // bar1: h_lds commit visible; globals stay in flight

        // ---- B: emission partial (sg rows) + 8 h-MFMAs (full 16-row tile) ----
        if (s > 0 && tid < 128) {
            int m_loc = tid >> 4, seg = tid & 15;
            const unsigned int* hr = &h_lds[(sg * 8 + m_loc) * 132 + seg * 8];
            const float* wc = &wcls_lds[seg * 16];
            float p = 0.f;
            #pragma unroll
            for (int j = 0; j < 8; ++j) {
                unsigned int w = hr[j];
                p += bf2f(w & 0xffffu) * wc[2 * j] + bf2f(w >> 16) * wc[2 * j + 1];
            }
            part_lds[m_loc][seg] = p;
        }
        {
            f32x4 acc = sg ? acc_xB : acc_xA;
            #pragma unroll
            for (int kih = 0; kih < 8; ++kih) {
                s16x8 a = *(const s16x8*)&h_lds[n * 132 + kih * 16 + kq * 4];
                s16x8 b = *(const s16x8*)&w_lds[(((wv * 16) + 8 + kih) * 64 + l) * 4];
                acc = __builtin_amdgcn_mfma_f32_16x16x32_bf16(a, b, acc, 0, 0, 0);
            }
            #pragma unroll
            for (int r = 0; r < 4; ++r)
                g_lds[wv][kq * 4 + r][n] = acc[r];
        }

        wg_barrier_lds();   // bar2: g_lds/part_lds visible

        // ---- C: cell for sg's 8 rows + tagged ring stores ----
        if ((cb >> 3) == sg) {
            float gi = g_lds[0][cb][cu] + bias_lds[cu];
            float gf = g_lds[1][cb][cu] + bias_lds[16 + cu];
            float gg = g_lds[2][cb][cu] + bias_lds[32 + cu];
            float go = g_lds[3][cb][cu] + bias_lds[48 + cu];
            float cn = sigmoidf_(gf) * c_reg + sigmoidf_(gi) * tanhf(gg);
            c_reg = cn;
            float hn = sigmoidf_(go) * tanhf(cn);
            unsigned int hbits = (unsigned int)f2bf(hn);
            unsigned int other = (unsigned int)__shfl_down((int)hbits, 1);
            if ((cu & 1) == 0) {
                unsigned long long pk = (unsigned long long)(hbits | (other << 16))
                                      | ((unsigned long long)(s + 1) << 32);
                __hip_atomic_store(
                    rbase + ((size_t)(s & 1) * 16384) + (size_t)(gb0 + cb) * 128 + ug * 8 + (cu >> 1),
                    pk, __ATOMIC_RELAXED, __HIP_MEMORY_SCOPE_AGENT);
            }
        }

        // ---- EM: emission final for sg (global store, fire-and-forget) ----
        if (s > 0 && tid < 8) {
            float ssum = 0.f;
            #pragma unroll
            for (int q = 0; q < 16; ++q) ssum += part_lds[tid][q];
            int t_prev = dir ? (Lseq - s) : (s - 1);
            emout[((size_t)(gb0 + sg * 8 + tid) * Lseq + t_prev) * Tn + ug] = ssum;
        }

        // ---- E: x-MFMAs for sg's s+1 from the in-flight gather ----
        if (do_x) {
            f32x4 ax = {0.f, 0.f, 0.f, 0.f};
            #pragma unroll
            for (int ki = 0; ki < 8; ++ki) {
                s16x8 a = __builtin_bit_cast(s16x8, xg[ki]);
                s16x8 b = *(const s16x8*)&w_lds[((wv * 16 + ki) * 64 + l) * 4];
                ax = __builtin_amdgcn_mfma_f32_16x16x32_bf16(a, b, ax, 0, 0, 0);
            }
            if (sg) acc_xB = ax; else acc_xA = ax;
        }
        // token for sg's s+2 (consumed two halves later)
        if (s + 2 < Lseq) {
            int t2 = dir ? (Lseq - 3 - s) : (s + 2);
            int tok2 = bd[(size_t)(gb0 + sg * 8 + (n & 7)) * Lseq + t2];
            if (sg) tokB_next = tok2; else tokA_next = tok2;
        }

        // ---- F: validate the probe; retry pending words (1st retry immediate) ----
        if (i >= 1) {
            const unsigned long long want = (unsigned long long)(((i - 1) >> 1) + 1);
            unsigned int pend = 0xfu;
            int tries = 0;
            while (true) {
                #pragma unroll
                for (int j = 0; j < 4; ++j)
                    if ((pend & (1u << j)) && ((v[j] >> 32) == want))
                        pend &= ~(1u << j);
                if (!pend) break;
                if (tries++ > 0) __builtin_amdgcn_s_sleep(2);
                #pragma unroll
                for (int j = 0; j < 4; ++j)
                    if (pend & (1u << j))
                        v[j] = __hip_atomic_load(psrc + j, __ATOMIC_RELAXED,
                                                 __HIP_MEMORY_SCOPE_AGENT);
            }
        }
        // loop: next half commits v (the other stream), bar1 orders h_lds reuse
    }

    // ---- tail: v holds stream A step 511; fetch B step 511; emit t_tail ----
    {
        #pragma unroll
        for (int j = 0; j < 4; ++j)
            h_lds[rrow * 132 + rw0 + j] = (unsigned int)v[j];   // A rows 0-7
        const unsigned long long* psrc = rbase + (size_t)16384   // parity 511&1=1
            + (size_t)(gb0 + 8 + rrow) * 128 + rw0;
        unsigned long long w[4];
        const unsigned long long want = 512ull;
        #pragma unroll
        for (int j = 0; j < 4; ++j)
            w[j] = __hip_atomic_load(psrc + j, __ATOMIC_RELAXED, __HIP_MEMORY_SCOPE_AGENT);
        {
            unsigned int pend = 0xfu;
            int tries = 0;
            while (true) {
                #pragma unroll
                for (int j = 0; j < 4; ++j)
                    if ((pend & (1u << j)) && ((w[j] >> 32) == want))
                        pend &= ~(1u << j);
                if (!pend) break;
                if (tries++ > 0) __builtin_amdgcn_s_sleep(2);
                #pragma unroll
                for (int j = 0; j < 4; ++j)
                    if (pend & (1u << j))
                        w[j] = __hip_atomic_load(psrc + j, __ATOMIC_RELAXED,
                                                 __HIP_MEMORY_SCOPE_AGENT);
            }
        }
        #pragma unroll
        for (int j = 0; j < 4; ++j)
            h_lds[(8 + rrow) * 132 + rw0 + j] = (unsigned int)w[j];  // B rows 8-15
        __syncthreads();
        {
            const int em_m = tid >> 4, em_seg = tid & 15;
            const unsigned int* hr = &h_lds[em_m * 132 + em_seg * 8];
            const float* wc = &wcls_lds[em_seg * 16];
            float p = 0.f;
            #pragma unroll
            for (int j = 0; j < 8; ++j) {
                unsigned int vv = hr[j];
                p += bf2f(vv & 0xffffu) * wc[2 * j] + bf2f(vv >> 16) * wc[2 * j + 1];
            }
            part_lds[em_m][em_seg] = p;
        }
        __syncthreads();
        if (tid < 16) {
            float ssum = 0.f;
            #pragma unroll
            for (int q = 0; q < 16; ++q) ssum += part_lds[tid][q];
            int t_tail = dir ? 0 : (Lseq - 1);
            emout[((size_t)(gb0 + tid) * Lseq + t_tail) * Tn + ug] = ssum;
        }
    }
}

__global__ void golden_kernel(const int* __restrict__ tag,
                              const float* __restrict__ em_f,
                              const float* __restrict__ em_b,
                              const float* __restrict__ b_cls,
                              const float* __restrict__ trans,
                              float* __restrict__ golden)
{
    int b = blockIdx.x;
    int tid = threadIdx.x;
    float s = 0.f;
    for (int l = tid; l < Lseq; l += blockDim.x) {
        int tg = tag[b * Lseq + l];
        if (tg != 0) {
            int prev = (l == 0) ? START_TAG : tag[b * Lseq + l - 1];
            size_t e = ((size_t)b * Lseq + l) * Tn + tg;
            s += em_f[e] + em_b[e] + b_cls[tg] + trans[prev * Tn + tg];
        }
    }
    for (int off = 32; off > 0; off >>= 1) s += __shfl_down(s, off);
    __shared__ float red[4];
    if ((tid & 63) == 0) red[tid >> 6] = s;
    __syncthreads();
    if (tid == 0) atomicAdd(golden, red[0] + red[1] + red[2] + red[3]);
}

// CRF forward scan, emissions pre-staged in LDS (coalesced float4 adds),
// scan then runs register/LDS-local: no dependent global loads in the loop.
__global__ void crf_forward_kernel(const float* __restrict__ em_f,
                                   const float* __restrict__ em_b,
                                   const float* __restrict__ b_cls,
                                   const float* __restrict__ trans,
                                   const int* __restrict__ lengths,
                                   float* __restrict__ allpath)
{
    int b = blockIdx.x;
    int lane = threadIdx.x;
    __shared__ float ems[Lseq * Tn];   // 32 KB: em_f + em_b for this batch

    {
        const f32x4* pf = (const f32x4*)(em_f + (size_t)b * Lseq * Tn);
        const f32x4* pb = (const f32x4*)(em_b + (size_t)b * Lseq * Tn);
        f32x4* pd = (f32x4*)ems;
        for (int i = lane; i < Lseq * Tn / 4; i += 64) {
            f32x4 a = pf[i], c = pb[i];
            pd[i] = (f32x4){a[0] + c[0], a[1] + c[1], a[2] + c[2], a[3] + c[3]};
        }
    }
    __syncthreads();

    int j = lane & 15;
    float tcol[16];
    #pragma unroll
    for (int i = 0; i < 16; ++i) tcol[i] = trans[i * Tn + j];
    float bc = b_cls[j];
    float alpha = ems[j] + bc + tcol[START_TAG];
    int len = lengths[b];
    for (int t = 1; t < Lseq; ++t) {
        float av[16];
        float m = -1e30f;
        #pragma unroll
        for (int i = 0; i < 16; ++i) {
            av[i] = __shfl(alpha, i) + tcol[i];
            m = fmaxf(m, av[i]);
        }
        float sum = 0.f;
        #pragma unroll
        for (int i = 0; i < 16; ++i) sum += __expf(av[i] - m);
        float nv = ems[t * Tn + j] + bc + m + __logf(sum);
        alpha = (t < len) ? nv : alpha;
    }
    if (lane == END_TAG) atomicAdd(allpath, alpha);
}

__global__ void finalize_kernel(const float* __restrict__ scal, float* __restrict__ out) {
    out[0] = (scal[1] - scal[0]) / (float)Bsz;
}

extern "C" void kernel_launch(void* const* d_in, const int* in_sizes, int n_in,
                              void* d_out, int out_size, void* d_ws, size_t ws_size,
                              hipStream_t stream)
{
    (void)in_sizes; (void)n_in; (void)out_size; (void)ws_size;
    const int*   bd     = (const int*)d_in[0];
    const int*   tag    = (const int*)d_in[1];
    const float* emb    = (const float*)d_in[2];
    const float* w_ih_f = (const float*)d_in[3];
    const float* w_hh_f = (const float*)d_in[4];
    const float* b_f    = (const float*)d_in[5];
    const float* w_ih_b = (const float*)d_in[6];
    const float* w_hh_b = (const float*)d_in[7];
    const float* b_b    = (const float*)d_in[8];
    const float* w_cls  = (const float*)d_in[9];
    const float* b_cls  = (const float*)d_in[10];
    const float* trans  = (const float*)d_in[11];
    float* out = (float*)d_out;

    float* ws = (float*)d_ws;
    float* em_f = ws;                                        // 1048576 f
    float* em_b = em_f + (size_t)Bsz * Lseq * Tn;            // 1048576 f
    unsigned long long* ring =
        (unsigned long long*)(em_b + (size_t)Bsz * Lseq * Tn);  // 65536 x 8B (8B-aligned)
    float* scal = (float*)(ring + 65536);                    // 8 f
    int* lengths = (int*)(scal + 8);                         // 128
    unsigned int* wtile = (unsigned int*)(lengths + 128);    // 524288 u
    unsigned int* embb = wtile + (size_t)524288;             // 3840000 u

    // zero ring (tag 0 = invalid; kills cross-launch tag aliasing) + scal
    hipMemsetAsync(ring, 0, 65536 * 8 + 8 * sizeof(float), stream);

    embprep_kernel<<<2048, 256, 0, stream>>>(emb, embb, 30000 * 128);
    wprep_kernel<<<2048, 256, 0, stream>>>(w_ih_f, w_hh_f, w_ih_b, w_hh_b, wtile);
    lengths_kernel<<<Bsz, 256, 0, stream>>>(tag, lengths);

    void* kargs[] = {
        (void*)&bd, (void*)&embb, (void*)&wtile,
        (void*)&b_f, (void*)&b_b, (void*)&w_cls,
        (void*)&em_f, (void*)&em_b,
        (void*)&ring
    };
    hipLaunchCooperativeKernel((const void*)bilstm_persist,
                               dim3(256), dim3(256), kargs, 0, stream);

    golden_kernel<<<Bsz, 256, 0, stream>>>(tag, em_f, em_b, b_cls, trans, scal);
    crf_forward_kernel<<<Bsz, 64, 0, stream>>>(em_f, em_b, b_cls, trans, lengths, scal + 1);
    finalize_kernel<<<1, 1, 0, stream>>>(scal, out);
}

// Round 11
// 2177.826 us; speedup vs baseline: 1.2403x; 1.2403x over previous
//
#include <hip/hip_runtime.h>

#define Bsz 128
#define Lseq 512
#define Hdim 256
#define Tn 16
#define START_TAG 14
#define END_TAG 15

typedef float f32x4 __attribute__((ext_vector_type(4)));
typedef short s16x8 __attribute__((ext_vector_type(8)));

__device__ __forceinline__ unsigned short f2bf(float f) {
    unsigned int u = __builtin_bit_cast(unsigned int, f);
    u += 0x7fffu + ((u >> 16) & 1u);          // RNE
    return (unsigned short)(u >> 16);
}
__device__ __forceinline__ float bf2f(unsigned int bits16) {
    return __builtin_bit_cast(float, bits16 << 16);
}
__device__ __forceinline__ float sigmoidf_(float x) {
    return 1.0f / (1.0f + __expf(-x));
}

// emb fp32 [V*256] -> packed bf16 pairs [V*128]
__global__ void embprep_kernel(const float* __restrict__ emb,
                               unsigned int* __restrict__ embb, int n2) {
    int i = blockIdx.x * blockDim.x + threadIdx.x;
    int stride = gridDim.x * blockDim.x;
    for (; i < n2; i += stride)
        embb[i] = (unsigned int)f2bf(emb[2 * i]) | ((unsigned int)f2bf(emb[2 * i + 1]) << 16);
}

// wtile[dir][ug(16)][tl=gate(4)][ki(16)][lane(64)][4 uints] : MFMA B-frag order.
// lane l: n=l&15, kq=l>>4; uint j holds k-elems ki*32+kq*8+2j, +1 of col tl*256+ug*16+n.
__global__ void wprep_kernel(const float* __restrict__ wih_f, const float* __restrict__ whh_f,
                             const float* __restrict__ wih_b, const float* __restrict__ whh_b,
                             unsigned int* __restrict__ wtile) {
    int bid = blockIdx.x;                 // ((dir*16+ug)*4+tl)*16+ki
    int ki  = bid & 15;
    int tl  = (bid >> 4) & 3;
    int ug  = (bid >> 6) & 15;
    int dir = bid >> 10;
    int t = threadIdx.x;                  // 256 = lane(64) x j(4)
    int lane = t >> 2, j = t & 3;
    int n = lane & 15, kq = lane >> 4;
    int k0 = ki * 32 + kq * 8 + 2 * j;
    int col = tl * 256 + ug * 16 + n;
    const float* wih = dir ? wih_b : wih_f;
    const float* whh = dir ? whh_b : whh_f;
    float f0, f1;
    if (k0 < 256) { f0 = wih[col * 256 + k0];       f1 = wih[col * 256 + k0 + 1]; }
    else          { f0 = whh[col * 256 + k0 - 256]; f1 = whh[col * 256 + k0 - 255]; }
    wtile[(size_t)bid * 256 + t] = (unsigned int)f2bf(f0) | ((unsigned int)f2bf(f1) << 16);
}

__global__ void lengths_kernel(const int* __restrict__ tag, int* __restrict__ lengths) {
    int b = blockIdx.x;
    int tid = threadIdx.x;
    int cnt = 0;
    for (int l = tid; l < Lseq; l += blockDim.x)
        cnt += (tag[b * Lseq + l] != 0) ? 1 : 0;
    for (int off = 32; off > 0; off >>= 1) cnt += __shfl_down(cnt, off);
    __shared__ int red[4];
    if ((tid & 63) == 0) red[tid >> 6] = cnt;
    __syncthreads();
    if (tid == 0) lengths[b] = red[0] + red[1] + red[2] + red[3];
}

// Persistent BiLSTM, 256 WGs (1/CU). WG = dir(2) x bg(8: 16 batches) x ug(16: 16 units).
// Exchange h via TAGGED 64-bit relaxed agent-scope atomics: each ring word =
// (bf16 pair | (s+1)<<32); the tag travels with the data -> no drain, no flag,
// no separate poll trip. Contention control: first-attempt load issued only
// AFTER the x-half MFMAs (peers' stores get ~1-2k cy of flight); emission-final
// writes moved AFTER the probe issue (covers its RTT); retry loop re-probes
// once immediately, then backs off with s_sleep(2), reloading only pending
// words. Safety: a producer reaches step s only after tag-validating all of
// h_{s-1}, proving every peer finished reading h_{s-2} from the parity slot
// being overwritten.
__global__ __launch_bounds__(256, 1) void bilstm_persist(
    const int* __restrict__ bd,
    const unsigned int* __restrict__ embb,         // [V][128]
    const unsigned int* __restrict__ wtile,        // frag-ordered weights
    const float* __restrict__ b_f, const float* __restrict__ b_b,
    const float* __restrict__ w_cls,
    float* __restrict__ em_f, float* __restrict__ em_b,
    unsigned long long* __restrict__ ring)         // [2 dir][2 par][128 b][128 words]
{
    const int wg  = blockIdx.x;
    const int dir = wg >> 7;
    const int bg  = (wg >> 4) & 7;
    const int ug  = wg & 15;
    const int tid = threadIdx.x;
    const int gb0 = bg * 16;

    __shared__ unsigned int w_lds[16384];      // [4 tl][16 ki][64 lane][4]
    __shared__ unsigned int h_lds[16 * 132];   // [16 m][128 uints + 4 pad]
    __shared__ float g_lds[4][16][17];
    __shared__ float part_lds[16][17];
    __shared__ float bias_lds[64];
    __shared__ float wcls_lds[256];

    // ---- one-time staging ----
    {
        const unsigned int* wsrc = wtile + ((size_t)(dir * 16 + ug) << 14);
        for (int i = 0; i < 16; ++i) {
            int idx = tid + 256 * i;
            uint4 v4 = *(const uint4*)(wsrc + (size_t)idx * 4);
            *(uint4*)&w_lds[idx * 4] = v4;
        }
        if (tid < 64) {
            const float* bias = dir ? b_b : b_f;
            bias_lds[tid] = bias[(tid >> 4) * 256 + ug * 16 + (tid & 15)];
        }
        wcls_lds[tid] = w_cls[(size_t)ug * (2 * Hdim) + dir * Hdim + tid];
        // h_{-1} = 0
        for (int i = tid; i < 16 * 132; i += 256) h_lds[i] = 0;
    }

    // identities
    const int wv = tid >> 6;        // wave = gate
    const int l  = tid & 63;
    const int n  = l & 15;          // col-in-tile / batch m for A
    const int kq = l >> 4;
    const int cb = tid >> 4, cu = tid & 15;            // cell: (batch, unit)
    const int em_m = tid >> 4, em_seg = tid & 15;      // emission partial
    const int hm = tid >> 4, hj0 = (tid & 15) * 8;     // ring load mapping
    float c_reg = 0.f;
    float* emout = dir ? em_b : em_f;
    const int* bd_row = bd + (size_t)(gb0 + n) * Lseq; // token row for A-frag rows

    unsigned long long* rbase = ring + (size_t)dir * 2 * 16384;

    __syncthreads();   // w_lds/bias/wcls/h_lds ready

    // ---- prologue: acc_x for s=0 ----
    f32x4 acc_x = {0.f, 0.f, 0.f, 0.f};
    {
        const int t0 = dir ? (Lseq - 1) : 0;
        int tok = bd_row[t0];
        const unsigned int* xsrc = embb + (size_t)tok * 128 + kq * 4;
        #pragma unroll
        for (int ki = 0; ki < 8; ++ki) {
            uint4 xv = *(const uint4*)(xsrc + ki * 16);
            s16x8 a = __builtin_bit_cast(s16x8, xv);
            s16x8 b = *(const s16x8*)&w_lds[((wv * 16 + ki) * 64 + l) * 4];
            acc_x = __builtin_amdgcn_mfma_f32_16x16x32_bf16(a, b, acc_x, 0, 0, 0);
        }
    }
    // token for E(s=0) (gather target t=1), pipelined one step deep
    int tok_next = (Lseq > 1) ? bd_row[dir ? (Lseq - 2) : 1] : 0;

    unsigned long long v[8];     // tag-validated h words carried across iters

    for (int s = 0; s < Lseq; ++s) {
        // ---- A: commit validated h_{s-1} words -> LDS ----
        if (s > 0) {
            #pragma unroll
            for (int j = 0; j < 8; ++j)
                h_lds[hm * 132 + hj0 + j] = (unsigned int)v[j];
        }
        __syncthreads();

        // ---- B: emission partial (tag ug, h_{t_prev}) + 8 h-MFMAs ----
        if (s > 0) {
            const unsigned int* hr = &h_lds[em_m * 132 + em_seg * 8];
            const float* wc = &wcls_lds[em_seg * 16];
            float p = 0.f;
            #pragma unroll
            for (int j = 0; j < 8; ++j) {
                unsigned int w = hr[j];
                p += bf2f(w & 0xffffu) * wc[2 * j] + bf2f(w >> 16) * wc[2 * j + 1];
            }
            part_lds[em_m][em_seg] = p;
        }
        {
            f32x4 acc = acc_x;
            #pragma unroll
            for (int kih = 0; kih < 8; ++kih) {
                s16x8 a = *(const s16x8*)&h_lds[n * 132 + kih * 16 + kq * 4];
                s16x8 b = *(const s16x8*)&w_lds[(((wv * 16) + 8 + kih) * 64 + l) * 4];
                acc = __builtin_amdgcn_mfma_f32_16x16x32_bf16(a, b, acc, 0, 0, 0);
            }
            #pragma unroll
            for (int r = 0; r < 4; ++r)
                g_lds[wv][kq * 4 + r][n] = acc[r];
        }
        __syncthreads();

        // ---- C: cell update + tagged 64b h store ----
        {
            float gi = g_lds[0][cb][cu] + bias_lds[cu];
            float gf = g_lds[1][cb][cu] + bias_lds[16 + cu];
            float gg = g_lds[2][cb][cu] + bias_lds[32 + cu];
            float go = g_lds[3][cb][cu] + bias_lds[48 + cu];
            float cn = sigmoidf_(gf) * c_reg + sigmoidf_(gi) * tanhf(gg);
            c_reg = cn;
            float hn = sigmoidf_(go) * tanhf(cn);
            unsigned int hbits = (unsigned int)f2bf(hn);
            unsigned int other = (unsigned int)__shfl_down((int)hbits, 1);
            if ((cu & 1) == 0) {
                unsigned long long pk = (unsigned long long)(hbits | (other << 16))
                                      | ((unsigned long long)(s + 1) << 32);
                __hip_atomic_store(
                    rbase + ((size_t)(s & 1) * 16384) + (size_t)(gb0 + cb) * 128 + ug * 8 + (cu >> 1),
                    pk, __ATOMIC_RELAXED, __HIP_MEMORY_SCOPE_AGENT);
            }
        }

        // ---- E: x-half MFMAs for s+1 (tok pre-fetched; peers' stores in flight) ----
        if (s + 1 < Lseq) {
            const unsigned int* xsrc = embb + (size_t)tok_next * 128 + kq * 4;
            f32x4 ax = {0.f, 0.f, 0.f, 0.f};
            #pragma unroll
            for (int ki = 0; ki < 8; ++ki) {
                uint4 xv = *(const uint4*)(xsrc + ki * 16);
                s16x8 a = __builtin_bit_cast(s16x8, xv);
                s16x8 b = *(const s16x8*)&w_lds[((wv * 16 + ki) * 64 + l) * 4];
                ax = __builtin_amdgcn_mfma_f32_16x16x32_bf16(a, b, ax, 0, 0, 0);
            }
            acc_x = ax;
        }
        if (s + 2 < Lseq)
            tok_next = bd_row[dir ? (Lseq - 3 - s) : (s + 2)];   // consumed next step

        // ---- D: first-attempt loads of h_s (issued late: mostly validates) ----
        const unsigned long long* src =
            rbase + ((size_t)(s & 1) * 16384) + (size_t)(gb0 + hm) * 128 + hj0;
        #pragma unroll
        for (int j = 0; j < 8; ++j)
            v[j] = __hip_atomic_load(src + j, __ATOMIC_RELAXED, __HIP_MEMORY_SCOPE_AGENT);

        // ---- EM: emission final (covers the probe's round trip) ----
        if (s > 0 && tid < 16) {
            float ssum = 0.f;
            #pragma unroll
            for (int q = 0; q < 16; ++q) ssum += part_lds[tid][q];
            int t_prev = dir ? (Lseq - s) : (s - 1);
            emout[((size_t)(gb0 + tid) * Lseq + t_prev) * Tn + ug] = ssum;
        }

        // ---- F: validate tags; retry pending words (1st retry immediate) ----
        {
            const unsigned long long want = (unsigned long long)(s + 1);
            unsigned int pend = 0xffu;
            int tries = 0;
            while (true) {
                #pragma unroll
                for (int j = 0; j < 8; ++j)
                    if ((pend & (1u << j)) && ((v[j] >> 32) == want))
                        pend &= ~(1u << j);
                if (!pend) break;
                if (tries++ > 0) __builtin_amdgcn_s_sleep(2);
                #pragma unroll
                for (int j = 0; j < 8; ++j)
                    if (pend & (1u << j))
                        v[j] = __hip_atomic_load(src + j, __ATOMIC_RELAXED,
                                                 __HIP_MEMORY_SCOPE_AGENT);
            }
        }
        // no barrier here: B(s)'s trailing barrier orders h_lds reuse at A(s+1)
    }

    // ---- tail: emission for h_{L-1} (v holds tag-512-validated words) ----
    {
        #pragma unroll
        for (int j = 0; j < 8; ++j)
            h_lds[hm * 132 + hj0 + j] = (unsigned int)v[j];
        __syncthreads();
        {
            const unsigned int* hr = &h_lds[em_m * 132 + em_seg * 8];
            const float* wc = &wcls_lds[em_seg * 16];
            float p = 0.f;
            #pragma unroll
            for (int j = 0; j < 8; ++j) {
                unsigned int vv = hr[j];
                p += bf2f(vv & 0xffffu) * wc[2 * j] + bf2f(vv >> 16) * wc[2 * j + 1];
            }
            part_lds[em_m][em_seg] = p;
        }
        __syncthreads();
        if (tid < 16) {
            float ssum = 0.f;
            #pragma unroll
            for (int q = 0; q < 16; ++q) ssum += part_lds[tid][q];
            int t_tail = dir ? 0 : (Lseq - 1);
            emout[((size_t)(gb0 + tid) * Lseq + t_tail) * Tn + ug] = ssum;
        }
    }
}

__global__ void golden_kernel(const int* __restrict__ tag,
                              const float* __restrict__ em_f,
                              const float* __restrict__ em_b,
                              const float* __restrict__ b_cls,
                              const float* __restrict__ trans,
                              float* __restrict__ golden)
{
    int b = blockIdx.x;
    int tid = threadIdx.x;
    float s = 0.f;
    for (int l = tid; l < Lseq; l += blockDim.x) {
        int tg = tag[b * Lseq + l];
        if (tg != 0) {
            int prev = (l == 0) ? START_TAG : tag[b * Lseq + l - 1];
            size_t e = ((size_t)b * Lseq + l) * Tn + tg;
            s += em_f[e] + em_b[e] + b_cls[tg] + trans[prev * Tn + tg];
        }
    }
    for (int off = 32; off > 0; off >>= 1) s += __shfl_down(s, off);
    __shared__ float red[4];
    if ((tid & 63) == 0) red[tid >> 6] = s;
    __syncthreads();
    if (tid == 0) atomicAdd(golden, red[0] + red[1] + red[2] + red[3]);
}

// CRF forward scan, emissions pre-staged in LDS (coalesced float4 adds),
// scan then runs register/LDS-local: no dependent global loads in the loop.
__global__ void crf_forward_kernel(const float* __restrict__ em_f,
                                   const float* __restrict__ em_b,
                                   const float* __restrict__ b_cls,
                                   const float* __restrict__ trans,
                                   const int* __restrict__ lengths,
                                   float* __restrict__ allpath)
{
    int b = blockIdx.x;
    int lane = threadIdx.x;
    __shared__ float ems[Lseq * Tn];   // 32 KB: em_f + em_b for this batch

    {
        const f32x4* pf = (const f32x4*)(em_f + (size_t)b * Lseq * Tn);
        const f32x4* pb = (const f32x4*)(em_b + (size_t)b * Lseq * Tn);
        f32x4* pd = (f32x4*)ems;
        for (int i = lane; i < Lseq * Tn / 4; i += 64) {
            f32x4 a = pf[i], c = pb[i];
            pd[i] = (f32x4){a[0] + c[0], a[1] + c[1], a[2] + c[2], a[3] + c[3]};
        }
    }
    __syncthreads();

    int j = lane & 15;
    float tcol[16];
    #pragma unroll
    for (int i = 0; i < 16; ++i) tcol[i] = trans[i * Tn + j];
    float bc = b_cls[j];
    float alpha = ems[j] + bc + tcol[START_TAG];
    int len = lengths[b];
    for (int t = 1; t < Lseq; ++t) {
        float av[16];
        float m = -1e30f;
        #pragma unroll
        for (int i = 0; i < 16; ++i) {
            av[i] = __shfl(alpha, i) + tcol[i];
            m = fmaxf(m, av[i]);
        }
        float sum = 0.f;
        #pragma unroll
        for (int i = 0; i < 16; ++i) sum += __expf(av[i] - m);
        float nv = ems[t * Tn + j] + bc + m + __logf(sum);
        alpha = (t < len) ? nv : alpha;
    }
    if (lane == END_TAG) atomicAdd(allpath, alpha);
}

__global__ void finalize_kernel(const float* __restrict__ scal, float* __restrict__ out) {
    out[0] = (scal[1] - scal[0]) / (float)Bsz;
}

extern "C" void kernel_launch(void* const* d_in, const int* in_sizes, int n_in,
                              void* d_out, int out_size, void* d_ws, size_t ws_size,
                              hipStream_t stream)
{
    (void)in_sizes; (void)n_in; (void)out_size; (void)ws_size;
    const int*   bd     = (const int*)d_in[0];
    const int*   tag    = (const int*)d_in[1];
    const float* emb    = (const float*)d_in[2];
    const float* w_ih_f = (const float*)d_in[3];
    const float* w_hh_f = (const float*)d_in[4];
    const float* b_f    = (const float*)d_in[5];
    const float* w_ih_b = (const float*)d_in[6];
    const float* w_hh_b = (const float*)d_in[7];
    const float* b_b    = (const float*)d_in[8];
    const float* w_cls  = (const float*)d_in[9];
    const float* b_cls  = (const float*)d_in[10];
    const float* trans  = (const float*)d_in[11];
    float* out = (float*)d_out;

    float* ws = (float*)d_ws;
    float* em_f = ws;                                        // 1048576 f
    float* em_b = em_f + (size_t)Bsz * Lseq * Tn;            // 1048576 f
    unsigned long long* ring =
        (unsigned long long*)(em_b + (size_t)Bsz * Lseq * Tn);  // 65536 x 8B (8B-aligned)
    float* scal = (float*)(ring + 65536);                    // 8 f
    int* lengths = (int*)(scal + 8);                         // 128
    unsigned int* wtile = (unsigned int*)(lengths + 128);    // 524288 u
    unsigned int* embb = wtile + (size_t)524288;             // 3840000 u

    // zero ring (tag 0 = invalid; kills cross-launch tag aliasing) + scal
    hipMemsetAsync(ring, 0, 65536 * 8 + 8 * sizeof(float), stream);

    embprep_kernel<<<2048, 256, 0, stream>>>(emb, embb, 30000 * 128);
    wprep_kernel<<<2048, 256, 0, stream>>>(w_ih_f, w_hh_f, w_ih_b, w_hh_b, wtile);
    lengths_kernel<<<Bsz, 256, 0, stream>>>(tag, lengths);

    void* kargs[] = {
        (void*)&bd, (void*)&embb, (void*)&wtile,
        (void*)&b_f, (void*)&b_b, (void*)&w_cls,
        (void*)&em_f, (void*)&em_b,
        (void*)&ring
    };
    hipLaunchCooperativeKernel((const void*)bilstm_persist,
                               dim3(256), dim3(256), kargs, 0, stream);

    golden_kernel<<<Bsz, 256, 0, stream>>>(tag, em_f, em_b, b_cls, trans, scal);
    crf_forward_kernel<<<Bsz, 64, 0, stream>>>(em_f, em_b, b_cls, trans, lengths, scal + 1);
    finalize_kernel<<<1, 1, 0, stream>>>(scal, out);
}